// Round 4
// baseline (257.886 us; speedup 1.0000x reference)
//
#include <hip/hip_runtime.h>

// NCC weight loss, fused single-kernel. v5 (from v4 @ 88.6us):
//  - Phase C restructured: 128 threads x (2 cols x 2 y-rows) = 4 outputs/thread;
//    the 6-row sliding window serves both y-rows -> LDS reads 25->15 b64/output
//    pair stream (Phase C pipe cost ~700 -> ~420 cy/block-iter).
//  - ZCH 32 -> 16: grid (7,12,20) = 1680 blocks -> ~6.6/CU, dynamic smoothing
//    of the frozen 3-vs-4 block imbalance that set v4's wall.
//  - Same software-pipelined global loads + lgkm-only raw barriers as v4.
// Dims fixed: (N=2, C=1, D=160, H=192, W=224), win=5, fp32.
#define N_  2
#define D_  160
#define H_  192
#define W_  224
#define TW  32            // output tile width  (x)
#define TH  16            // output tile height (y)
#define ZCH 16            // z-chunk per block
#define NZC (D_/ZCH)      // 10
#define HR  (TH+4)        // 20 halo rows
#define HC  (TW+4)        // 36 halo cols (row stride 144B, 16B-aligned)
#define PL  (H_*W_)       // 43008 plane stride
#define TOT (N_*D_*H_*W_) // 13,762,560

#define BAR() asm volatile("s_waitcnt lgkmcnt(0)\n\ts_barrier" ::: "memory")

__global__ __launch_bounds__(256, 4) void ncc_kernel(
    const float* __restrict__ I, const float* __restrict__ J,
    const float* __restrict__ Wm, float* __restrict__ out)
{
    __shared__ __align__(16) float zsL[5][HR][HC]; // z-summed quantities
    __shared__ __align__(16) float sx [5][HR][HC]; // x-box-summed
    __shared__ float red[4];

    const int tid = threadIdx.x;
    const int bx = blockIdx.x, by = blockIdx.y;
    const int n  = blockIdx.z / NZC;
    const int c0 = (blockIdx.z % NZC) * ZCH;
    const int nbase = n * D_ * PL;

    // ---- Phase A: 180 threads, 4 halo columns each (two aligned float2 loads)
    const bool aAct = tid < 180;
    const int arow = tid / 9;                 // 0..19
    const int ag   = tid % 9;                 // 0..8
    const int ah   = by * TH - 2 + arow;
    const int ahc  = min(max(ah, 0), H_ - 1);
    const int aw0  = bx * TW - 2 + 4 * ag;    // even
    const bool mH  = (ah == ahc);
    const bool mW0 = (aw0 >= 0);              // pair0 = cols aw0, aw0+1
    const bool mW1 = (aw0 + 3 < W_);          // pair1 = cols aw0+2, aw0+3
    const int awc0 = max(aw0, 0);
    const int awc1 = min(aw0 + 2, W_ - 4);
    const int preA0 = nbase + ahc * W_ + awc0;   // + z*PL
    const int preA1 = nbase + ahc * W_ + awc1;

    // ---- Phase B: 160 threads, 4 x-outputs each
    const bool bAct = tid < 160;
    const int brow = tid >> 3;                // 0..19
    const int bxo  = (tid & 7) * 4;           // 0..28

    // ---- Phase C: 128 threads, 2 cols x 2 y-rows each
    const bool cAct = tid < 128;
    const int crp = tid >> 4;                 // 0..7  (row pair)
    const int cr0 = 2 * crp;                  // local top row (0,2,..,14)
    const int cx0 = (tid & 15) * 2;           // 0..30
    const int ch0 = by * TH + cr0;
    const int cw  = bx * TW + cx0;            // even -> float2-aligned
    const int preW = nbase + ch0 * W_ + cw;   // + zo*PL ; row1 = +W_

    // per-column z-ring of raw I,J (5 deep) + incremental z-sums (5 quantities)
    float rI[4][5], rJ[4][5], zs[5][4];
#pragma unroll
    for (int c = 0; c < 4; ++c)
#pragma unroll
        for (int k = 0; k < 5; ++k) { rI[c][k] = 0.f; rJ[c][k] = 0.f; }
#pragma unroll
    for (int a = 0; a < 5; ++a)
#pragma unroll
        for (int c = 0; c < 4; ++c) zs[a][c] = 0.f;

    float acc = 0.f;
    const float inv125 = 1.0f / 125.0f;

    // current-plane raw values (masked), consumed by this iteration's Phase A
    float cI[4] = {0.f,0.f,0.f,0.f}, cJ[4] = {0.f,0.f,0.f,0.f};
    {
        const int z0 = c0 - 2;
        const int zc = min(max(z0, 0), D_ - 1);
        const bool mZ = (z0 == zc);
        const int zoff = zc * PL;
        if (aAct) {
            const float2 i0 = *(const float2*)&I[preA0 + zoff];
            const float2 i1 = *(const float2*)&I[preA1 + zoff];
            const float2 j0 = *(const float2*)&J[preA0 + zoff];
            const float2 j1 = *(const float2*)&J[preA1 + zoff];
            const float f0 = (mH && mW0 && mZ) ? 1.f : 0.f;
            const float f1 = (mH && mW1 && mZ) ? 1.f : 0.f;
            cI[0]=i0.x*f0; cI[1]=i0.y*f0; cI[2]=i1.x*f1; cI[3]=i1.y*f1;
            cJ[0]=j0.x*f0; cJ[1]=j0.y*f0; cJ[2]=j1.x*f1; cJ[3]=j1.y*f1;
        }
    }
    // Wm tiles (2 rows) for this iteration's Phase C
    float wm0x=0.f, wm0y=0.f, wm1x=0.f, wm1y=0.f;

    for (int s = 0; s < ZCH + 4; ++s) {
        // ---- prefetch next z-plane (z+1) into registers — clamped + masked;
        //      stays in flight across both barriers (lgkm-only waits)
        const int zn  = c0 - 1 + s;
        const int znc = min(max(zn, 0), D_ - 1);
        const bool mZn = (zn == znc);
        const int zoffn = znc * PL;
        float2 pi0, pi1, pj0, pj1;
        if (aAct) {
            pi0 = *(const float2*)&I[preA0 + zoffn];
            pi1 = *(const float2*)&I[preA1 + zoffn];
            pj0 = *(const float2*)&J[preA0 + zoffn];
            pj1 = *(const float2*)&J[preA1 + zoffn];
        } else {
            pi0 = pi1 = pj0 = pj1 = make_float2(0.f, 0.f);
        }
        // ---- prefetch next iteration's Wm tiles (2 rows, clamped z)
        float2 wmN0 = make_float2(0.f, 0.f), wmN1 = make_float2(0.f, 0.f);
        if (cAct) {
            const int zon  = c0 - 3 + s;
            const int zonc = min(max(zon, 0), D_ - 1);
            wmN0 = *(const float2*)&Wm[preW + zonc * PL];
            wmN1 = *(const float2*)&Wm[preW + W_ + zonc * PL];
        }

        // ---- Phase A: integrate current plane into z-ring, stage z-sums (b128)
        if (aAct) {
#pragma unroll
            for (int c = 0; c < 4; ++c) {
                const float vi = cI[c], vj = cJ[c];
                const float oi = rI[c][0], oj = rJ[c][0];
                zs[0][c] += vi - oi;
                zs[1][c] += vj - oj;
                zs[2][c] += vi*vi - oi*oi;
                zs[3][c] += vj*vj - oj*oj;
                zs[4][c] += vi*vj - oi*oj;
#pragma unroll
                for (int k = 0; k < 4; ++k) { rI[c][k]=rI[c][k+1]; rJ[c][k]=rJ[c][k+1]; }
                rI[c][4] = vi; rJ[c][4] = vj;
            }
#pragma unroll
            for (int a = 0; a < 5; ++a)
                *(float4*)&zsL[a][arow][4*ag] =
                    make_float4(zs[a][0], zs[a][1], zs[a][2], zs[a][3]);
        }
        BAR();   // lgkm drain only — prefetched globals stay in flight

        // ---- Phase B: x box-sum (36 -> 32), 4 outputs per thread
        if (bAct) {
#pragma unroll
            for (int a = 0; a < 5; ++a) {
                const float4 v0 = *(const float4*)&zsL[a][brow][bxo];
                const float4 v1 = *(const float4*)&zsL[a][brow][bxo + 4];
                const float m  = v0.y + v0.z + v0.w;
                const float u1 = v1.x + v1.y;
                const float u2 = u1 + v1.z;
                *(float4*)&sx[a][brow][bxo] =
                    make_float4(v0.x + m + v1.x, m + u1,
                                (v0.z + v0.w) + u2, v0.w + (u2 + v1.w));
            }
        }
        BAR();

        // ---- Phase C: 6-row sliding y-sum -> 2 y-rows x 2 cols per thread
        if (cAct && s >= 4) {
            float2 ST[5], SB[5];
#pragma unroll
            for (int a = 0; a < 5; ++a) {
                const float2 r0 = *(const float2*)&sx[a][cr0    ][cx0];
                const float2 r1 = *(const float2*)&sx[a][cr0 + 1][cx0];
                const float2 r2 = *(const float2*)&sx[a][cr0 + 2][cx0];
                const float2 r3 = *(const float2*)&sx[a][cr0 + 3][cx0];
                const float2 r4 = *(const float2*)&sx[a][cr0 + 4][cx0];
                const float2 r5 = *(const float2*)&sx[a][cr0 + 5][cx0];
                float2 t;                       // rows cr0..cr0+4
                t.x = ((r0.x + r1.x) + (r2.x + r3.x)) + r4.x;
                t.y = ((r0.y + r1.y) + (r2.y + r3.y)) + r4.y;
                ST[a] = t;
                SB[a] = make_float2(t.x - r0.x + r5.x,   // rows cr0+1..cr0+5
                                    t.y - r0.y + r5.y);
            }
            {   // output row ch0, cols cw, cw+1
                const float crx = ST[4].x - ST[0].x * ST[1].x * inv125;
                const float vix = ST[2].x - ST[0].x * ST[0].x * inv125;
                const float vjx = ST[3].x - ST[1].x * ST[1].x * inv125;
                acc += wm0x * (crx * crx) * __builtin_amdgcn_rcpf(vix * vjx + 1e-8f);
                const float cry = ST[4].y - ST[0].y * ST[1].y * inv125;
                const float viy = ST[2].y - ST[0].y * ST[0].y * inv125;
                const float vjy = ST[3].y - ST[1].y * ST[1].y * inv125;
                acc += wm0y * (cry * cry) * __builtin_amdgcn_rcpf(viy * vjy + 1e-8f);
            }
            {   // output row ch0+1
                const float crx = SB[4].x - SB[0].x * SB[1].x * inv125;
                const float vix = SB[2].x - SB[0].x * SB[0].x * inv125;
                const float vjx = SB[3].x - SB[1].x * SB[1].x * inv125;
                acc += wm1x * (crx * crx) * __builtin_amdgcn_rcpf(vix * vjx + 1e-8f);
                const float cry = SB[4].y - SB[0].y * SB[1].y * inv125;
                const float viy = SB[2].y - SB[0].y * SB[0].y * inv125;
                const float vjy = SB[3].y - SB[1].y * SB[1].y * inv125;
                acc += wm1y * (cry * cry) * __builtin_amdgcn_rcpf(viy * vjy + 1e-8f);
            }
        }

        // ---- rotate pipeline registers (apply masks to prefetched plane)
        {
            const float f0 = (mH && mW0 && mZn) ? 1.f : 0.f;
            const float f1 = (mH && mW1 && mZn) ? 1.f : 0.f;
            cI[0]=pi0.x*f0; cI[1]=pi0.y*f0; cI[2]=pi1.x*f1; cI[3]=pi1.y*f1;
            cJ[0]=pj0.x*f0; cJ[1]=pj0.y*f0; cJ[2]=pj1.x*f1; cJ[3]=pj1.y*f1;
        }
        wm0x = wmN0.x; wm0y = wmN0.y; wm1x = wmN1.x; wm1y = wmN1.y;
        // Hazards: C reads sx vs next B writes sx -> separated by next BAR1.
        // Next A writes zsL vs this B reads zsL -> separated by BAR2.
    }

    // Block reduction: wave64 shuffle, then cross-wave via LDS
#pragma unroll
    for (int off = 32; off > 0; off >>= 1)
        acc += __shfl_down(acc, off, 64);
    const int wave = tid >> 6;
    const int lane = tid & 63;
    if (lane == 0) red[wave] = acc;
    __syncthreads();
    if (tid == 0) {
        const float t = red[0] + red[1] + red[2] + red[3];
        atomicAdd(out, t * (-1.0f / (float)TOT));
    }
}

extern "C" void kernel_launch(void* const* d_in, const int* in_sizes, int n_in,
                              void* d_out, int out_size, void* d_ws, size_t ws_size,
                              hipStream_t stream)
{
    const float* I  = (const float*)d_in[0];
    const float* J  = (const float*)d_in[1];
    const float* Wm = (const float*)d_in[2];
    float* out = (float*)d_out;

    hipMemsetAsync(out, 0, sizeof(float), stream);

    dim3 grid(W_ / TW, H_ / TH, N_ * NZC);  // (7, 12, 20) = 1680 blocks
    dim3 block(256);
    hipLaunchKernelGGL(ncc_kernel, grid, block, 0, stream, I, J, Wm, out);
}

// Round 5
// 199.766 us; speedup vs baseline: 1.2909x; 1.2909x over previous
//
#include <hip/hip_runtime.h>

// NCC weight loss, fused single-kernel. v6 = v4 (89us, best) with ZCH 32->20:
// 1344 blocks (7,12,16) -> 1024 resident + 320-block dispatch queue, which
// dynamically backfills CUs and smooths v4's frozen 3-vs-4 block imbalance.
// v5's Phase-C restructure is REVERTED (it unbalanced per-wave load: waves 0-1
// carried A+B+C while wave 3 idled -> +48% per-iter wall).
// Dims fixed: (N=2, C=1, D=160, H=192, W=224), win=5, fp32.
#define N_  2
#define D_  160
#define H_  192
#define W_  224
#define TW  32            // output tile width  (x)
#define TH  16            // output tile height (y)
#define ZCH 20            // z-chunk per block
#define NZC (D_/ZCH)      // 8
#define HR  (TH+4)        // 20 halo rows
#define HC  (TW+4)        // 36 halo cols (row stride 144B, 16B-aligned)
#define PL  (H_*W_)       // 43008 plane stride
#define TOT (N_*D_*H_*W_) // 13,762,560

#define BAR() asm volatile("s_waitcnt lgkmcnt(0)\n\ts_barrier" ::: "memory")

__global__ __launch_bounds__(256, 4) void ncc_kernel(
    const float* __restrict__ I, const float* __restrict__ J,
    const float* __restrict__ Wm, float* __restrict__ out)
{
    __shared__ __align__(16) float zsL[5][HR][HC]; // z-summed quantities
    __shared__ __align__(16) float sx [5][HR][HC]; // x-box-summed
    __shared__ float red[4];

    const int tid = threadIdx.x;
    const int bx = blockIdx.x, by = blockIdx.y;
    const int n  = blockIdx.z / NZC;
    const int c0 = (blockIdx.z % NZC) * ZCH;
    const int nbase = n * D_ * PL;

    // ---- Phase A: 180 threads, 4 halo columns each (two aligned float2 loads)
    const bool aAct = tid < 180;
    const int arow = tid / 9;                 // 0..19
    const int ag   = tid % 9;                 // 0..8
    const int ah   = by * TH - 2 + arow;
    const int ahc  = min(max(ah, 0), H_ - 1);
    const int aw0  = bx * TW - 2 + 4 * ag;    // even
    const bool mH  = (ah == ahc);
    const bool mW0 = (aw0 >= 0);              // pair0 = cols aw0, aw0+1
    const bool mW1 = (aw0 + 3 < W_);          // pair1 = cols aw0+2, aw0+3
    const int awc0 = max(aw0, 0);
    const int awc1 = min(aw0 + 2, W_ - 4);
    const int preA0 = nbase + ahc * W_ + awc0;   // + z*PL
    const int preA1 = nbase + ahc * W_ + awc1;

    // ---- Phase B: 160 threads, 4 x-outputs each
    const bool bAct = tid < 160;
    const int brow = tid >> 3;                // 0..19
    const int bxo  = (tid & 7) * 4;           // 0..28

    // ---- Phase C: 256 threads, 2 outputs each (all 4 waves active)
    const int cty = tid >> 4;                 // 0..15
    const int cx0 = (tid & 15) * 2;           // 0..30
    const int ch  = by * TH + cty;
    const int cw  = bx * TW + cx0;            // even
    const int preW = nbase + ch * W_ + cw;    // + zo*PL

    // per-column z-ring of raw I,J (5 deep) + incremental z-sums (5 quantities)
    float rI[4][5], rJ[4][5], zs[5][4];
#pragma unroll
    for (int c = 0; c < 4; ++c)
#pragma unroll
        for (int k = 0; k < 5; ++k) { rI[c][k] = 0.f; rJ[c][k] = 0.f; }
#pragma unroll
    for (int a = 0; a < 5; ++a)
#pragma unroll
        for (int c = 0; c < 4; ++c) zs[a][c] = 0.f;

    float acc = 0.f;
    const float inv125 = 1.0f / 125.0f;

    // current-plane raw values (masked), consumed by this iteration's Phase A
    float cI[4] = {0.f,0.f,0.f,0.f}, cJ[4] = {0.f,0.f,0.f,0.f};
    {
        const int z0 = c0 - 2;
        const int zc = min(max(z0, 0), D_ - 1);
        const bool mZ = (z0 == zc);
        const int zoff = zc * PL;
        if (aAct) {
            const float2 i0 = *(const float2*)&I[preA0 + zoff];
            const float2 i1 = *(const float2*)&I[preA1 + zoff];
            const float2 j0 = *(const float2*)&J[preA0 + zoff];
            const float2 j1 = *(const float2*)&J[preA1 + zoff];
            const float f0 = (mH && mW0 && mZ) ? 1.f : 0.f;
            const float f1 = (mH && mW1 && mZ) ? 1.f : 0.f;
            cI[0]=i0.x*f0; cI[1]=i0.y*f0; cI[2]=i1.x*f1; cI[3]=i1.y*f1;
            cJ[0]=j0.x*f0; cJ[1]=j0.y*f0; cJ[2]=j1.x*f1; cJ[3]=j1.y*f1;
        }
    }
    float wmCx = 0.f, wmCy = 0.f;   // Wm tile for this iteration's Phase C

    for (int s = 0; s < ZCH + 4; ++s) {
        // ---- prefetch next z-plane (z+1) into registers — clamped + masked;
        //      stays in flight across both barriers (lgkm-only waits)
        const int zn  = c0 - 1 + s;
        const int znc = min(max(zn, 0), D_ - 1);
        const bool mZn = (zn == znc);
        const int zoffn = znc * PL;
        float2 pi0, pi1, pj0, pj1;
        if (aAct) {
            pi0 = *(const float2*)&I[preA0 + zoffn];
            pi1 = *(const float2*)&I[preA1 + zoffn];
            pj0 = *(const float2*)&J[preA0 + zoffn];
            pj1 = *(const float2*)&J[preA1 + zoffn];
        } else {
            pi0 = pi1 = pj0 = pj1 = make_float2(0.f, 0.f);
        }
        // ---- prefetch next iteration's Wm tile (clamped, unconditional)
        const int zon  = c0 - 3 + s;
        const int zonc = min(max(zon, 0), D_ - 1);
        const float2 wmN = *(const float2*)&Wm[preW + zonc * PL];

        // ---- Phase A: integrate current plane into z-ring, stage z-sums (b128)
        if (aAct) {
#pragma unroll
            for (int c = 0; c < 4; ++c) {
                const float vi = cI[c], vj = cJ[c];
                const float oi = rI[c][0], oj = rJ[c][0];
                zs[0][c] += vi - oi;
                zs[1][c] += vj - oj;
                zs[2][c] += vi*vi - oi*oi;
                zs[3][c] += vj*vj - oj*oj;
                zs[4][c] += vi*vj - oi*oj;
#pragma unroll
                for (int k = 0; k < 4; ++k) { rI[c][k]=rI[c][k+1]; rJ[c][k]=rJ[c][k+1]; }
                rI[c][4] = vi; rJ[c][4] = vj;
            }
#pragma unroll
            for (int a = 0; a < 5; ++a)
                *(float4*)&zsL[a][arow][4*ag] =
                    make_float4(zs[a][0], zs[a][1], zs[a][2], zs[a][3]);
        }
        BAR();   // lgkm drain only — prefetched globals stay in flight

        // ---- Phase B: x box-sum (36 -> 32), 4 outputs per thread
        if (bAct) {
#pragma unroll
            for (int a = 0; a < 5; ++a) {
                const float4 v0 = *(const float4*)&zsL[a][brow][bxo];
                const float4 v1 = *(const float4*)&zsL[a][brow][bxo + 4];
                const float m  = v0.y + v0.z + v0.w;
                const float u1 = v1.x + v1.y;
                const float u2 = u1 + v1.z;
                *(float4*)&sx[a][brow][bxo] =
                    make_float4(v0.x + m + v1.x, m + u1,
                                (v0.z + v0.w) + u2, v0.w + (u2 + v1.w));
            }
        }
        BAR();

        // ---- Phase C: y box-sum + cc + weighted accumulate, all 256 threads
        if (s >= 4) {   // uniform: output plane zo = c0-4+s is in range
            float2 S[5];
#pragma unroll
            for (int a = 0; a < 5; ++a) {
                float2 v = *(const float2*)&sx[a][cty][cx0];
#pragma unroll
                for (int k = 1; k < 5; ++k) {
                    const float2 w = *(const float2*)&sx[a][cty + k][cx0];
                    v.x += w.x; v.y += w.y;
                }
                S[a] = v;
            }
            {
                const float cr = S[4].x - S[0].x * S[1].x * inv125;
                const float vi = S[2].x - S[0].x * S[0].x * inv125;
                const float vj = S[3].x - S[1].x * S[1].x * inv125;
                acc += wmCx * (cr * cr) * __builtin_amdgcn_rcpf(vi * vj + 1e-8f);
            }
            {
                const float cr = S[4].y - S[0].y * S[1].y * inv125;
                const float vi = S[2].y - S[0].y * S[0].y * inv125;
                const float vj = S[3].y - S[1].y * S[1].y * inv125;
                acc += wmCy * (cr * cr) * __builtin_amdgcn_rcpf(vi * vj + 1e-8f);
            }
        }

        // ---- rotate pipeline registers (apply masks to prefetched plane)
        {
            const float f0 = (mH && mW0 && mZn) ? 1.f : 0.f;
            const float f1 = (mH && mW1 && mZn) ? 1.f : 0.f;
            cI[0]=pi0.x*f0; cI[1]=pi0.y*f0; cI[2]=pi1.x*f1; cI[3]=pi1.y*f1;
            cJ[0]=pj0.x*f0; cJ[1]=pj0.y*f0; cJ[2]=pj1.x*f1; cJ[3]=pj1.y*f1;
        }
        wmCx = wmN.x; wmCy = wmN.y;
        // Hazards: C reads sx vs next B writes sx -> separated by next BAR1.
        // Next A writes zsL vs this B reads zsL -> separated by BAR2.
    }

    // Block reduction: wave64 shuffle, then cross-wave via LDS
#pragma unroll
    for (int off = 32; off > 0; off >>= 1)
        acc += __shfl_down(acc, off, 64);
    const int wave = tid >> 6;
    const int lane = tid & 63;
    if (lane == 0) red[wave] = acc;
    __syncthreads();
    if (tid == 0) {
        const float t = red[0] + red[1] + red[2] + red[3];
        atomicAdd(out, t * (-1.0f / (float)TOT));
    }
}

extern "C" void kernel_launch(void* const* d_in, const int* in_sizes, int n_in,
                              void* d_out, int out_size, void* d_ws, size_t ws_size,
                              hipStream_t stream)
{
    const float* I  = (const float*)d_in[0];
    const float* J  = (const float*)d_in[1];
    const float* Wm = (const float*)d_in[2];
    float* out = (float*)d_out;

    hipMemsetAsync(out, 0, sizeof(float), stream);

    dim3 grid(W_ / TW, H_ / TH, N_ * NZC);  // (7, 12, 16) = 1344 blocks
    dim3 block(256);
    hipLaunchKernelGGL(ncc_kernel, grid, block, 0, stream, I, J, Wm, out);
}

// Round 6
// 197.869 us; speedup vs baseline: 1.3033x; 1.0096x over previous
//
#include <hip/hip_runtime.h>

// NCC weight loss, fused single-kernel. v7 (from v6 @ 88.5us):
//  - TH 16 -> 24 (768 voxels/plane-iter). Phase C = 256 threads x (1 col x
//    3 y-rows) with a 7-row sliding window: reads/voxel 12.5 -> 11.7 AND the
//    1-col-per-lane pattern is bank-conflict-free (kills the 4.3M conflict cy).
//  - A: 252 thr x 4 cols (28 halo rows x 9 groups), same register z-ring.
//    B: 224 thr x 4 x-outputs. All phases ~4-wave balanced.
//  - LDS 40.3KB -> still 4 blocks/CU (161.3KB < 160KiB=163840B).
//  - Same pipelined global prefetch + lgkm-only raw barriers as v4/v6. ZCH=20.
// Dims fixed: (N=2, C=1, D=160, H=192, W=224), win=5, fp32.
#define N_  2
#define D_  160
#define H_  192
#define W_  224
#define TW  32            // output tile width  (x)
#define TH  24            // output tile height (y)
#define ZCH 20            // z-chunk per block
#define NZC (D_/ZCH)      // 8
#define HR  (TH+4)        // 28 halo rows
#define HC  (TW+4)        // 36 halo cols (row stride 144B, 16B-aligned)
#define PL  (H_*W_)       // 43008 plane stride
#define TOT (N_*D_*H_*W_) // 13,762,560

#define BAR() asm volatile("s_waitcnt lgkmcnt(0)\n\ts_barrier" ::: "memory")

__global__ __launch_bounds__(256, 4) void ncc_kernel(
    const float* __restrict__ I, const float* __restrict__ J,
    const float* __restrict__ Wm, float* __restrict__ out)
{
    __shared__ __align__(16) float zsL[5][HR][HC]; // z-summed quantities
    __shared__ __align__(16) float sx [5][HR][HC]; // x-box-summed
    __shared__ float red[4];

    const int tid = threadIdx.x;
    const int bx = blockIdx.x, by = blockIdx.y;
    const int n  = blockIdx.z / NZC;
    const int c0 = (blockIdx.z % NZC) * ZCH;
    const int nbase = n * D_ * PL;

    // ---- Phase A: 252 threads, 4 halo columns each (two aligned float2 loads)
    const bool aAct = tid < 252;
    const int arow = tid / 9;                 // 0..27
    const int ag   = tid % 9;                 // 0..8
    const int ah   = by * TH - 2 + arow;
    const int ahc  = min(max(ah, 0), H_ - 1);
    const int aw0  = bx * TW - 2 + 4 * ag;    // even
    const bool mH  = (ah == ahc);
    const bool mW0 = (aw0 >= 0);              // pair0 = cols aw0, aw0+1
    const bool mW1 = (aw0 + 3 < W_);          // pair1 = cols aw0+2, aw0+3
    const int awc0 = max(aw0, 0);
    const int awc1 = min(aw0 + 2, W_ - 4);
    const int preA0 = nbase + ahc * W_ + awc0;   // + z*PL
    const int preA1 = nbase + ahc * W_ + awc1;

    // ---- Phase B: 224 threads, 4 x-outputs each
    const bool bAct = tid < 224;
    const int brow = tid >> 3;                // 0..27
    const int bxo  = (tid & 7) * 4;           // 0..28

    // ---- Phase C: 256 threads, 1 col x 3 y-rows each (7-row window)
    const int cg   = tid >> 5;                // 0..7 (row triple)
    const int cr0  = 3 * cg;                  // local top row 0,3,...,21
    const int ccol = tid & 31;                // 0..31
    const int ch0  = by * TH + cr0;
    const int cw   = bx * TW + ccol;
    const int preW = nbase + ch0 * W_ + cw;   // + zo*PL ; rows +W_, +2*W_

    // per-column z-ring of raw I,J (5 deep) + incremental z-sums (5 quantities)
    float rI[4][5], rJ[4][5], zs[5][4];
#pragma unroll
    for (int c = 0; c < 4; ++c)
#pragma unroll
        for (int k = 0; k < 5; ++k) { rI[c][k] = 0.f; rJ[c][k] = 0.f; }
#pragma unroll
    for (int a = 0; a < 5; ++a)
#pragma unroll
        for (int c = 0; c < 4; ++c) zs[a][c] = 0.f;

    float acc = 0.f;
    const float inv125 = 1.0f / 125.0f;

    // current-plane raw values (masked), consumed by this iteration's Phase A
    float cI[4] = {0.f,0.f,0.f,0.f}, cJ[4] = {0.f,0.f,0.f,0.f};
    {
        const int z0 = c0 - 2;
        const int zc = min(max(z0, 0), D_ - 1);
        const bool mZ = (z0 == zc);
        const int zoff = zc * PL;
        if (aAct) {
            const float2 i0 = *(const float2*)&I[preA0 + zoff];
            const float2 i1 = *(const float2*)&I[preA1 + zoff];
            const float2 j0 = *(const float2*)&J[preA0 + zoff];
            const float2 j1 = *(const float2*)&J[preA1 + zoff];
            const float f0 = (mH && mW0 && mZ) ? 1.f : 0.f;
            const float f1 = (mH && mW1 && mZ) ? 1.f : 0.f;
            cI[0]=i0.x*f0; cI[1]=i0.y*f0; cI[2]=i1.x*f1; cI[3]=i1.y*f1;
            cJ[0]=j0.x*f0; cJ[1]=j0.y*f0; cJ[2]=j1.x*f1; cJ[3]=j1.y*f1;
        }
    }
    float wm0 = 0.f, wm1 = 0.f, wm2 = 0.f;  // Wm rows for this iter's Phase C

    for (int s = 0; s < ZCH + 4; ++s) {
        // ---- prefetch next z-plane (z+1) into registers — clamped + masked;
        //      stays in flight across both barriers (lgkm-only waits)
        const int zn  = c0 - 1 + s;
        const int znc = min(max(zn, 0), D_ - 1);
        const bool mZn = (zn == znc);
        const int zoffn = znc * PL;
        float2 pi0, pi1, pj0, pj1;
        if (aAct) {
            pi0 = *(const float2*)&I[preA0 + zoffn];
            pi1 = *(const float2*)&I[preA1 + zoffn];
            pj0 = *(const float2*)&J[preA0 + zoffn];
            pj1 = *(const float2*)&J[preA1 + zoffn];
        } else {
            pi0 = pi1 = pj0 = pj1 = make_float2(0.f, 0.f);
        }
        // ---- prefetch next iteration's Wm rows (clamped z, all threads)
        const int zon  = c0 - 3 + s;
        const int zonc = min(max(zon, 0), D_ - 1);
        const int wmo  = preW + zonc * PL;
        const float wn0 = Wm[wmo];
        const float wn1 = Wm[wmo + W_];
        const float wn2 = Wm[wmo + 2 * W_];

        // ---- Phase A: integrate current plane into z-ring, stage z-sums (b128)
        if (aAct) {
#pragma unroll
            for (int c = 0; c < 4; ++c) {
                const float vi = cI[c], vj = cJ[c];
                const float oi = rI[c][0], oj = rJ[c][0];
                zs[0][c] += vi - oi;
                zs[1][c] += vj - oj;
                zs[2][c] += vi*vi - oi*oi;
                zs[3][c] += vj*vj - oj*oj;
                zs[4][c] += vi*vj - oi*oj;
#pragma unroll
                for (int k = 0; k < 4; ++k) { rI[c][k]=rI[c][k+1]; rJ[c][k]=rJ[c][k+1]; }
                rI[c][4] = vi; rJ[c][4] = vj;
            }
#pragma unroll
            for (int a = 0; a < 5; ++a)
                *(float4*)&zsL[a][arow][4*ag] =
                    make_float4(zs[a][0], zs[a][1], zs[a][2], zs[a][3]);
        }
        BAR();   // lgkm drain only — prefetched globals stay in flight

        // ---- Phase B: x box-sum (36 -> 32), 4 outputs per thread
        if (bAct) {
#pragma unroll
            for (int a = 0; a < 5; ++a) {
                const float4 v0 = *(const float4*)&zsL[a][brow][bxo];
                const float4 v1 = *(const float4*)&zsL[a][brow][bxo + 4];
                const float m  = v0.y + v0.z + v0.w;
                const float u1 = v1.x + v1.y;
                const float u2 = u1 + v1.z;
                *(float4*)&sx[a][brow][bxo] =
                    make_float4(v0.x + m + v1.x, m + u1,
                                (v0.z + v0.w) + u2, v0.w + (u2 + v1.w));
            }
        }
        BAR();

        // ---- Phase C: 7-row sliding y-sum -> 3 y-rows x 1 col per thread
        if (s >= 4) {   // uniform: output plane zo = c0-4+s is in range
            float S0[5], S1[5], S2[5];
#pragma unroll
            for (int a = 0; a < 5; ++a) {
                const float r0 = sx[a][cr0    ][ccol];
                const float r1 = sx[a][cr0 + 1][ccol];
                const float r2 = sx[a][cr0 + 2][ccol];
                const float r3 = sx[a][cr0 + 3][ccol];
                const float r4 = sx[a][cr0 + 4][ccol];
                const float r5 = sx[a][cr0 + 5][ccol];
                const float r6 = sx[a][cr0 + 6][ccol];
                const float t0 = ((r0 + r1) + (r2 + r3)) + r4;
                S0[a] = t0;
                const float t1 = t0 - r0 + r5;
                S1[a] = t1;
                S2[a] = t1 - r1 + r6;
            }
            {
                const float cr = S0[4] - S0[0] * S0[1] * inv125;
                const float vi = S0[2] - S0[0] * S0[0] * inv125;
                const float vj = S0[3] - S0[1] * S0[1] * inv125;
                acc += wm0 * (cr * cr) * __builtin_amdgcn_rcpf(vi * vj + 1e-8f);
            }
            {
                const float cr = S1[4] - S1[0] * S1[1] * inv125;
                const float vi = S1[2] - S1[0] * S1[0] * inv125;
                const float vj = S1[3] - S1[1] * S1[1] * inv125;
                acc += wm1 * (cr * cr) * __builtin_amdgcn_rcpf(vi * vj + 1e-8f);
            }
            {
                const float cr = S2[4] - S2[0] * S2[1] * inv125;
                const float vi = S2[2] - S2[0] * S2[0] * inv125;
                const float vj = S2[3] - S2[1] * S2[1] * inv125;
                acc += wm2 * (cr * cr) * __builtin_amdgcn_rcpf(vi * vj + 1e-8f);
            }
        }

        // ---- rotate pipeline registers (apply masks to prefetched plane)
        {
            const float f0 = (mH && mW0 && mZn) ? 1.f : 0.f;
            const float f1 = (mH && mW1 && mZn) ? 1.f : 0.f;
            cI[0]=pi0.x*f0; cI[1]=pi0.y*f0; cI[2]=pi1.x*f1; cI[3]=pi1.y*f1;
            cJ[0]=pj0.x*f0; cJ[1]=pj0.y*f0; cJ[2]=pj1.x*f1; cJ[3]=pj1.y*f1;
        }
        wm0 = wn0; wm1 = wn1; wm2 = wn2;
        // Hazards: C reads sx vs next B writes sx -> separated by next BAR1.
        // Next A writes zsL vs this B reads zsL -> separated by BAR2.
    }

    // Block reduction: wave64 shuffle, then cross-wave via LDS
#pragma unroll
    for (int off = 32; off > 0; off >>= 1)
        acc += __shfl_down(acc, off, 64);
    const int wave = tid >> 6;
    const int lane = tid & 63;
    if (lane == 0) red[wave] = acc;
    __syncthreads();
    if (tid == 0) {
        const float t = red[0] + red[1] + red[2] + red[3];
        atomicAdd(out, t * (-1.0f / (float)TOT));
    }
}

extern "C" void kernel_launch(void* const* d_in, const int* in_sizes, int n_in,
                              void* d_out, int out_size, void* d_ws, size_t ws_size,
                              hipStream_t stream)
{
    const float* I  = (const float*)d_in[0];
    const float* J  = (const float*)d_in[1];
    const float* Wm = (const float*)d_in[2];
    float* out = (float*)d_out;

    hipMemsetAsync(out, 0, sizeof(float), stream);

    dim3 grid(W_ / TW, H_ / TH, N_ * NZC);  // (7, 8, 16) = 896 blocks
    dim3 block(256);
    hipLaunchKernelGGL(ncc_kernel, grid, block, 0, stream, I, J, Wm, out);
}

// Round 7
// 197.024 us; speedup vs baseline: 1.3089x; 1.0043x over previous
//
#include <hip/hip_runtime.h>

// NCC weight loss, fused single-kernel. v8 (from v7 @ 86.5us):
//  - Phase B dedup: B-thread = A-thread (row,g). Outputs 4g-4..4g-1 computed
//    from left-neighbor b128 (LDS) + OWN zs registers (the right 4 cols are
//    this thread's just-computed z-sums). LDS reads in B: 10 -> 5 b128.
//  - ZCH 20 -> 16: grid (7,8,20) = 1120 blocks = 1024 resident + 96 queued ->
//    dispatch-queue backfill dissolves v7's frozen 4-vs-3 block imbalance
//    (v6's verified mechanism), at fill cost 1.25 vs 1.20.
//  - Rest identical to v7: TH=24, C = 256 thr x (1 col x 3 y-rows, 7-row
//    sliding window, conflict-free), pipelined global prefetch, lgkm-only
//    raw barriers.
// Dims fixed: (N=2, C=1, D=160, H=192, W=224), win=5, fp32.
#define N_  2
#define D_  160
#define H_  192
#define W_  224
#define TW  32            // output tile width  (x)
#define TH  24            // output tile height (y)
#define ZCH 16            // z-chunk per block
#define NZC (D_/ZCH)      // 10
#define HR  (TH+4)        // 28 halo rows
#define HC  (TW+4)        // 36 halo cols (row stride 144B, 16B-aligned)
#define PL  (H_*W_)       // 43008 plane stride
#define TOT (N_*D_*H_*W_) // 13,762,560

#define BAR() asm volatile("s_waitcnt lgkmcnt(0)\n\ts_barrier" ::: "memory")

__global__ __launch_bounds__(256, 4) void ncc_kernel(
    const float* __restrict__ I, const float* __restrict__ J,
    const float* __restrict__ Wm, float* __restrict__ out)
{
    __shared__ __align__(16) float zsL[5][HR][HC]; // z-summed quantities
    __shared__ __align__(16) float sx [5][HR][HC]; // x-box-summed
    __shared__ float red[4];

    const int tid = threadIdx.x;
    const int bx = blockIdx.x, by = blockIdx.y;
    const int n  = blockIdx.z / NZC;
    const int c0 = (blockIdx.z % NZC) * ZCH;
    const int nbase = n * D_ * PL;

    // ---- Phase A: 252 threads, 4 halo columns each (two aligned float2 loads)
    const bool aAct = tid < 252;
    const int arow = tid / 9;                 // 0..27
    const int ag   = tid % 9;                 // 0..8
    const int ah   = by * TH - 2 + arow;
    const int ahc  = min(max(ah, 0), H_ - 1);
    const int aw0  = bx * TW - 2 + 4 * ag;    // even
    const bool mH  = (ah == ahc);
    const bool mW0 = (aw0 >= 0);              // pair0 = cols aw0, aw0+1
    const bool mW1 = (aw0 + 3 < W_);          // pair1 = cols aw0+2, aw0+3
    const int awc0 = max(aw0, 0);
    const int awc1 = min(aw0 + 2, W_ - 4);
    const int preA0 = nbase + ahc * W_ + awc0;   // + z*PL
    const int preA1 = nbase + ahc * W_ + awc1;

    // ---- Phase B: same threads as A, g>=1 active (left-b128 + own registers)
    const bool bAct = aAct && (ag >= 1);

    // ---- Phase C: 256 threads, 1 col x 3 y-rows each (7-row window)
    const int cg   = tid >> 5;                // 0..7 (row triple)
    const int cr0  = 3 * cg;                  // local top row 0,3,...,21
    const int ccol = tid & 31;                // 0..31
    const int ch0  = by * TH + cr0;
    const int cw   = bx * TW + ccol;
    const int preW = nbase + ch0 * W_ + cw;   // + zo*PL ; rows +W_, +2*W_

    // per-column z-ring of raw I,J (5 deep) + incremental z-sums (5 quantities)
    float rI[4][5], rJ[4][5], zs[5][4];
#pragma unroll
    for (int c = 0; c < 4; ++c)
#pragma unroll
        for (int k = 0; k < 5; ++k) { rI[c][k] = 0.f; rJ[c][k] = 0.f; }
#pragma unroll
    for (int a = 0; a < 5; ++a)
#pragma unroll
        for (int c = 0; c < 4; ++c) zs[a][c] = 0.f;

    float acc = 0.f;
    const float inv125 = 1.0f / 125.0f;

    // current-plane raw values (masked), consumed by this iteration's Phase A
    float cI[4] = {0.f,0.f,0.f,0.f}, cJ[4] = {0.f,0.f,0.f,0.f};
    {
        const int z0 = c0 - 2;
        const int zc = min(max(z0, 0), D_ - 1);
        const bool mZ = (z0 == zc);
        const int zoff = zc * PL;
        if (aAct) {
            const float2 i0 = *(const float2*)&I[preA0 + zoff];
            const float2 i1 = *(const float2*)&I[preA1 + zoff];
            const float2 j0 = *(const float2*)&J[preA0 + zoff];
            const float2 j1 = *(const float2*)&J[preA1 + zoff];
            const float f0 = (mH && mW0 && mZ) ? 1.f : 0.f;
            const float f1 = (mH && mW1 && mZ) ? 1.f : 0.f;
            cI[0]=i0.x*f0; cI[1]=i0.y*f0; cI[2]=i1.x*f1; cI[3]=i1.y*f1;
            cJ[0]=j0.x*f0; cJ[1]=j0.y*f0; cJ[2]=j1.x*f1; cJ[3]=j1.y*f1;
        }
    }
    float wm0 = 0.f, wm1 = 0.f, wm2 = 0.f;  // Wm rows for this iter's Phase C

    for (int s = 0; s < ZCH + 4; ++s) {
        // ---- prefetch next z-plane (z+1) into registers — clamped + masked;
        //      stays in flight across both barriers (lgkm-only waits)
        const int zn  = c0 - 1 + s;
        const int znc = min(max(zn, 0), D_ - 1);
        const bool mZn = (zn == znc);
        const int zoffn = znc * PL;
        float2 pi0, pi1, pj0, pj1;
        if (aAct) {
            pi0 = *(const float2*)&I[preA0 + zoffn];
            pi1 = *(const float2*)&I[preA1 + zoffn];
            pj0 = *(const float2*)&J[preA0 + zoffn];
            pj1 = *(const float2*)&J[preA1 + zoffn];
        } else {
            pi0 = pi1 = pj0 = pj1 = make_float2(0.f, 0.f);
        }
        // ---- prefetch next iteration's Wm rows (clamped z, all threads)
        const int zon  = c0 - 3 + s;
        const int zonc = min(max(zon, 0), D_ - 1);
        const int wmo  = preW + zonc * PL;
        const float wn0 = Wm[wmo];
        const float wn1 = Wm[wmo + W_];
        const float wn2 = Wm[wmo + 2 * W_];

        // ---- Phase A: integrate current plane into z-ring, stage z-sums (b128)
        if (aAct) {
#pragma unroll
            for (int c = 0; c < 4; ++c) {
                const float vi = cI[c], vj = cJ[c];
                const float oi = rI[c][0], oj = rJ[c][0];
                zs[0][c] += vi - oi;
                zs[1][c] += vj - oj;
                zs[2][c] += vi*vi - oi*oi;
                zs[3][c] += vj*vj - oj*oj;
                zs[4][c] += vi*vj - oi*oj;
#pragma unroll
                for (int k = 0; k < 4; ++k) { rI[c][k]=rI[c][k+1]; rJ[c][k]=rJ[c][k+1]; }
                rI[c][4] = vi; rJ[c][4] = vj;
            }
#pragma unroll
            for (int a = 0; a < 5; ++a)
                *(float4*)&zsL[a][arow][4*ag] =
                    make_float4(zs[a][0], zs[a][1], zs[a][2], zs[a][3]);
        }
        BAR();   // lgkm drain only — prefetched globals stay in flight

        // ---- Phase B: x box-sum; left-neighbor b128 from LDS + own registers.
        //      Thread (row,g) produces output cols 4g-4..4g-1 (zsL-local),
        //      window for col c is zsL cols c..c+4.
        if (bAct) {
#pragma unroll
            for (int a = 0; a < 5; ++a) {
                const float4 L = *(const float4*)&zsL[a][arow][4*ag - 4];
                const float o0 = zs[a][0], o1 = zs[a][1];
                const float o2 = zs[a][2], o3 = zs[a][3];
                const float m    = L.y + L.z + L.w;
                const float s01  = o0 + o1;
                const float s012 = s01 + o2;
                *(float4*)&sx[a][arow][4*ag - 4] =
                    make_float4(L.x + m + o0,          // cols 4g-4..4g   window
                                m + s01,               // 4g-3..4g+1
                                (L.z + L.w) + s012,    // 4g-2..4g+2
                                L.w + (s012 + o3));    // 4g-1..4g+3
            }
        }
        BAR();

        // ---- Phase C: 7-row sliding y-sum -> 3 y-rows x 1 col per thread
        if (s >= 4) {   // uniform: output plane zo = c0-4+s is in range
            float S0[5], S1[5], S2[5];
#pragma unroll
            for (int a = 0; a < 5; ++a) {
                const float r0 = sx[a][cr0    ][ccol];
                const float r1 = sx[a][cr0 + 1][ccol];
                const float r2 = sx[a][cr0 + 2][ccol];
                const float r3 = sx[a][cr0 + 3][ccol];
                const float r4 = sx[a][cr0 + 4][ccol];
                const float r5 = sx[a][cr0 + 5][ccol];
                const float r6 = sx[a][cr0 + 6][ccol];
                const float t0 = ((r0 + r1) + (r2 + r3)) + r4;
                S0[a] = t0;
                const float t1 = t0 - r0 + r5;
                S1[a] = t1;
                S2[a] = t1 - r1 + r6;
            }
            {
                const float cr = S0[4] - S0[0] * S0[1] * inv125;
                const float vi = S0[2] - S0[0] * S0[0] * inv125;
                const float vj = S0[3] - S0[1] * S0[1] * inv125;
                acc += wm0 * (cr * cr) * __builtin_amdgcn_rcpf(vi * vj + 1e-8f);
            }
            {
                const float cr = S1[4] - S1[0] * S1[1] * inv125;
                const float vi = S1[2] - S1[0] * S1[0] * inv125;
                const float vj = S1[3] - S1[1] * S1[1] * inv125;
                acc += wm1 * (cr * cr) * __builtin_amdgcn_rcpf(vi * vj + 1e-8f);
            }
            {
                const float cr = S2[4] - S2[0] * S2[1] * inv125;
                const float vi = S2[2] - S2[0] * S2[0] * inv125;
                const float vj = S2[3] - S2[1] * S2[1] * inv125;
                acc += wm2 * (cr * cr) * __builtin_amdgcn_rcpf(vi * vj + 1e-8f);
            }
        }

        // ---- rotate pipeline registers (apply masks to prefetched plane)
        {
            const float f0 = (mH && mW0 && mZn) ? 1.f : 0.f;
            const float f1 = (mH && mW1 && mZn) ? 1.f : 0.f;
            cI[0]=pi0.x*f0; cI[1]=pi0.y*f0; cI[2]=pi1.x*f1; cI[3]=pi1.y*f1;
            cJ[0]=pj0.x*f0; cJ[1]=pj0.y*f0; cJ[2]=pj1.x*f1; cJ[3]=pj1.y*f1;
        }
        wm0 = wn0; wm1 = wn1; wm2 = wn2;
        // Hazards: C reads sx vs next B writes sx -> separated by next BAR1.
        // Next A writes zsL vs this B reads zsL -> separated by BAR2.
        // B reads its OWN zs registers (no hazard) + left-neighbor zsL (BAR1).
    }

    // Block reduction: wave64 shuffle, then cross-wave via LDS
#pragma unroll
    for (int off = 32; off > 0; off >>= 1)
        acc += __shfl_down(acc, off, 64);
    const int wave = tid >> 6;
    const int lane = tid & 63;
    if (lane == 0) red[wave] = acc;
    __syncthreads();
    if (tid == 0) {
        const float t = red[0] + red[1] + red[2] + red[3];
        atomicAdd(out, t * (-1.0f / (float)TOT));
    }
}

extern "C" void kernel_launch(void* const* d_in, const int* in_sizes, int n_in,
                              void* d_out, int out_size, void* d_ws, size_t ws_size,
                              hipStream_t stream)
{
    const float* I  = (const float*)d_in[0];
    const float* J  = (const float*)d_in[1];
    const float* Wm = (const float*)d_in[2];
    float* out = (float*)d_out;

    hipMemsetAsync(out, 0, sizeof(float), stream);

    dim3 grid(W_ / TW, H_ / TH, N_ * NZC);  // (7, 8, 20) = 1120 blocks
    dim3 block(256);
    hipLaunchKernelGGL(ncc_kernel, grid, block, 0, stream, I, J, Wm, out);
}